// Round 7
// baseline (218.107 us; speedup 1.0000x reference)
//
#include <hip/hip_runtime.h>

#define NN 100000
#define DD 128
#define EE 640000
#define BN_EPS 1e-3f
#define NBLK 391   // ceil(NN/256)

typedef __bf16 bf16x8 __attribute__((ext_vector_type(8)));
typedef float f32x4 __attribute__((ext_vector_type(4)));

// ---- workspace byte offsets ----
#define W1F_OFF 0u            // 128x128 bf16 frags    = 32768 B
#define W2F_OFF 32768u        // 256x128 bf16 frags    = 65536 B
#define B1F_OFF 98304u        // 128 f32
#define B2F_OFF 98816u        // 128 f32
#define T_OFF   99328u        // NN*128 bf16           = 25,600,000 B
#define DEG_OFF 25699328u     // NN int
#define OFFS_OFF 26099328u    // NN int
#define CUR_OFF 26499328u     // NN int
#define ELIST_OFF 26899328u   // EE int = 2,560,000 B
#define BSUM_OFF 29459328u    // NBLK int
#define BOFF_OFF 29461376u    // NBLK int
#define AGG_OFF 29464576u     // NN*128 bf16 = 25,600,000 B (end ~55.1 MB)

// tanh-form gelu: x * sigmoid(1.59576912*x + 0.07135481*x^3); max |err| vs exact ~3e-4
__device__ __forceinline__ float gelu_fast(float x) {
    float x3 = x * x * x;
    float z2 = 1.5957691216057308f * x + 0.07135481627002407f * x3;
    return x / (1.0f + __expf(-z2));
}

// bias fold: one wave per output column (256 waves total)
__global__ __launch_bounds__(256) void fold_bias_kernel(
    const float* __restrict__ g1, const float* __restrict__ be1,
    const float* __restrict__ m1, const float* __restrict__ v1,
    const float* __restrict__ W1, const float* __restrict__ b1,
    const float* __restrict__ g2, const float* __restrict__ be2,
    const float* __restrict__ m2, const float* __restrict__ v2,
    const float* __restrict__ W2, const float* __restrict__ b2,
    float* __restrict__ b1f, float* __restrict__ b2f)
{
    const int w = (blockIdx.x * 256 + threadIdx.x) >> 6;   // 0..255
    const int lane = threadIdx.x & 63;
    if (w < 128) {
        float acc = 0.f;
        for (int k = lane; k < 128; k += 64) {
            float s = g1[k] * rsqrtf(v1[k] + BN_EPS);
            float sh = be1[k] - m1[k] * s;
            acc += sh * W1[k * 128 + w];
        }
#pragma unroll
        for (int off = 32; off > 0; off >>= 1) acc += __shfl_down(acc, off);
        if (lane == 0) b1f[w] = acc + b1[w];
    } else {
        const int n = w - 128;
        float acc = 0.f;
        for (int k = lane; k < 256; k += 64) {
            float s = g2[k] * rsqrtf(v2[k] + BN_EPS);
            float sh = be2[k] - m2[k] * s;
            acc += sh * W2[k * 128 + n];
        }
#pragma unroll
        for (int off = 32; off > 0; off >>= 1) acc += __shfl_down(acc, off);
        if (lane == 0) b2f[n] = acc + b2[n];
    }
}

// weight fold into MFMA B-fragment order; grid covers 16384+32768 elements exactly.
// B-frag: lane l holds B[k=(l>>4)*8+i][n=(l&15)] per (kt,nt).
// agg-half rows of W2 permuted: physical col p -> logical col (p&7)*16 + (p>>3)
__global__ __launch_bounds__(256) void fold_w_kernel(
    const float* __restrict__ g1, const float* __restrict__ v1,
    const float* __restrict__ W1,
    const float* __restrict__ g2, const float* __restrict__ v2,
    const float* __restrict__ W2,
    __bf16* __restrict__ W1f, __bf16* __restrict__ W2f)
{
    int tid = blockIdx.x * 256 + threadIdx.x;
    if (tid < 16384) {
        int idx = tid;
        int i = idx & 7, l = (idx >> 3) & 63, nt = (idx >> 9) & 7, kt = idx >> 12;
        int k = kt * 32 + (l >> 4) * 8 + i;
        int n = nt * 16 + (l & 15);
        float s = g1[k] * rsqrtf(v1[k] + BN_EPS);
        W1f[idx] = (__bf16)(s * W1[k * 128 + n]);
    } else {
        int idx = tid - 16384;
        int i = idx & 7, l = (idx >> 3) & 63, nt = (idx >> 9) & 7, kt = idx >> 12;
        int n = nt * 16 + (l & 15);
        int row;
        if (kt < 4) {
            row = kt * 32 + (l >> 4) * 8 + i;
        } else {
            int q = (kt - 4) * 32 + (l >> 4) * 8 + i;      // physical agg col
            row = 128 + ((q & 7) * 16 + (q >> 3));          // logical W2 row
        }
        float s = g2[row] * rsqrtf(v2[row] + BN_EPS);
        W2f[idx] = (__bf16)(s * W2[row * 128 + n]);
    }
}

// t = gelu(X @ W1f + b1f); grid-stride over 16-row tiles, next-tile X prefetch,
// B-frags from L1 (W1f = 32 KB, L1-resident, shared by all waves).
// T stored bf16 with permuted cols: physical p -> logical (p&7)*16 + (p>>3)
__global__ __launch_bounds__(256, 3) void ffn1_kernel(
    const float* __restrict__ X, const __bf16* __restrict__ W1f,
    const float* __restrict__ b1f, __bf16* __restrict__ T)
{
    const int wave = threadIdx.x >> 6;
    const int lane = threadIdx.x & 63;
    const int c = lane & 15, kh = lane >> 4;

    float bias[8];
#pragma unroll
    for (int nt = 0; nt < 8; ++nt) bias[nt] = b1f[nt * 16 + c];

    const int NW = gridDim.x * 4;
    int tile = blockIdx.x * 4 + wave;

    f32x4 raw[8];
    if (tile * 16 < NN) {
        int rowA = tile * 16 + c; if (rowA >= NN) rowA = NN - 1;
        const float* xr = X + (size_t)rowA * DD + kh * 8;
#pragma unroll
        for (int q = 0; q < 4; ++q) {
            raw[2 * q]     = *(const f32x4*)(xr + q * 32);
            raw[2 * q + 1] = *(const f32x4*)(xr + q * 32 + 4);
        }
    }

    while (tile * 16 < NN) {
        bf16x8 af[4];
#pragma unroll
        for (int kt = 0; kt < 4; ++kt) {
            bf16x8 fa;
#pragma unroll
            for (int i = 0; i < 4; ++i) {
                fa[i]     = (__bf16)raw[2 * kt][i];
                fa[4 + i] = (__bf16)raw[2 * kt + 1][i];
            }
            af[kt] = fa;
        }
        const int curtile = tile;
        tile += NW;
        if (tile * 16 < NN) {   // prefetch next tile while MFMAs run
            int rowA = tile * 16 + c; if (rowA >= NN) rowA = NN - 1;
            const float* xr = X + (size_t)rowA * DD + kh * 8;
#pragma unroll
            for (int q = 0; q < 4; ++q) {
                raw[2 * q]     = *(const f32x4*)(xr + q * 32);
                raw[2 * q + 1] = *(const f32x4*)(xr + q * 32 + 4);
            }
        }

        f32x4 acc[8] = {};
#pragma unroll
        for (int kt = 0; kt < 4; ++kt)
#pragma unroll
            for (int nt = 0; nt < 8; ++nt) {
                bf16x8 bfr = *(const bf16x8*)(W1f + ((size_t)((kt * 8 + nt) * 64 + lane)) * 8);
                acc[nt] = __builtin_amdgcn_mfma_f32_16x16x32_bf16(af[kt], bfr, acc[nt], 0, 0, 0);
            }

#pragma unroll
        for (int r = 0; r < 4; ++r) {
            int row = curtile * 16 + kh * 4 + r;
            if (row < NN) {
                bf16x8 o;
#pragma unroll
                for (int nt = 0; nt < 8; ++nt)
                    o[nt] = (__bf16)gelu_fast(acc[nt][r] + bias[nt]);
                *(bf16x8*)(T + (size_t)row * DD + c * 8) = o;
            }
        }
    }
}

// deg[dst]++ over all edges
__global__ __launch_bounds__(256) void hist_kernel(const int* __restrict__ edges,
                                                   int* __restrict__ deg)
{
    int e = blockIdx.x * 256 + threadIdx.x;
    if (e < EE) atomicAdd(&deg[edges[e]], 1);
}

// phase 1: per-block sum of deg
__global__ __launch_bounds__(256) void scan_part_kernel(const int* __restrict__ deg,
                                                        int* __restrict__ bsum)
{
    int i = blockIdx.x * 256 + threadIdx.x;
    int v = (i < NN) ? deg[i] : 0;
#pragma unroll
    for (int off = 32; off > 0; off >>= 1) v += __shfl_down(v, off);
    __shared__ int ws[4];
    if ((threadIdx.x & 63) == 0) ws[threadIdx.x >> 6] = v;
    __syncthreads();
    if (threadIdx.x == 0) bsum[blockIdx.x] = ws[0] + ws[1] + ws[2] + ws[3];
}

// phase 2: single-block exclusive scan of NBLK block sums
__global__ __launch_bounds__(512) void scan_top_kernel(const int* __restrict__ bsum,
                                                       int* __restrict__ boff)
{
    __shared__ int s[512];
    const int t = threadIdx.x;
    int v = (t < NBLK) ? bsum[t] : 0;
    s[t] = v;
    __syncthreads();
    for (int off = 1; off < 512; off <<= 1) {
        int tmp = (t >= off) ? s[t - off] : 0;
        __syncthreads();
        s[t] += tmp;
        __syncthreads();
    }
    if (t < NBLK) boff[t] = s[t] - v;
}

// phase 3: per-block exclusive scan + block offset -> offs, cursor
__global__ __launch_bounds__(256) void scan_final_kernel(const int* __restrict__ deg,
                                                         const int* __restrict__ boff,
                                                         int* __restrict__ offs,
                                                         int* __restrict__ cursor)
{
    __shared__ int s[256];
    const int t = threadIdx.x;
    int i = blockIdx.x * 256 + t;
    int v = (i < NN) ? deg[i] : 0;
    s[t] = v;
    __syncthreads();
    for (int off = 1; off < 256; off <<= 1) {
        int tmp = (t >= off) ? s[t - off] : 0;
        __syncthreads();
        s[t] += tmp;
        __syncthreads();
    }
    int ex = s[t] - v + boff[blockIdx.x];
    if (i < NN) { offs[i] = ex; cursor[i] = ex; }
}

// CSR edge list: elist[offs[dst] ...] = src
__global__ __launch_bounds__(256) void build_kernel(const int* __restrict__ edges,
                                                    int* __restrict__ cursor,
                                                    int* __restrict__ elist)
{
    int e = blockIdx.x * 256 + threadIdx.x;
    if (e >= EE) return;
    int dst = edges[e];
    int src = edges[EE + e];
    int pos = atomicAdd(&cursor[dst], 1);
    elist[pos] = src;
}

// gather-mean: Agg[node] = mean of T[src] rows (permuted layout kept).
// 16 threads/node, 4-edge unroll for 4 independent loads in flight.
__global__ __launch_bounds__(256) void agg_kernel(
    const __bf16* __restrict__ T, const int* __restrict__ offs,
    const int* __restrict__ deg, const int* __restrict__ elist,
    __bf16* __restrict__ Agg)
{
    int t = blockIdx.x * 256 + threadIdx.x;
    int node = t >> 4, j = t & 15;
    if (node >= NN) return;
    const int beg = offs[node];
    const int d = deg[node];
    const int end = beg + d;
    float acc[8] = {};
    int e = beg;
    for (; e + 3 < end; e += 4) {
        int s0 = elist[e], s1 = elist[e + 1], s2 = elist[e + 2], s3 = elist[e + 3];
        bf16x8 v0 = *(const bf16x8*)(T + (size_t)s0 * DD + j * 8);
        bf16x8 v1 = *(const bf16x8*)(T + (size_t)s1 * DD + j * 8);
        bf16x8 v2 = *(const bf16x8*)(T + (size_t)s2 * DD + j * 8);
        bf16x8 v3 = *(const bf16x8*)(T + (size_t)s3 * DD + j * 8);
#pragma unroll
        for (int i = 0; i < 8; ++i)
            acc[i] += ((float)v0[i] + (float)v1[i]) + ((float)v2[i] + (float)v3[i]);
    }
    for (; e < end; ++e) {
        int s0 = elist[e];
        bf16x8 v0 = *(const bf16x8*)(T + (size_t)s0 * DD + j * 8);
#pragma unroll
        for (int i = 0; i < 8; ++i) acc[i] += (float)v0[i];
    }
    const float inv = 1.0f / fmaxf((float)d, 1.0f);
    bf16x8 o;
#pragma unroll
    for (int i = 0; i < 8; ++i) o[i] = (__bf16)(acc[i] * inv);
    *(bf16x8*)(Agg + (size_t)node * DD + j * 8) = o;
}

// out = gelu([X, Agg] @ W2f + b2f); grid-stride 16-row tiles; per-block:
// waves {0,1}=rows tile A colhalf {0,1}, {2,3}=rows tile B colhalf {0,1}.
// B working set 32 KB/colhalf from L1/L2; X+Agg prefetched.
__global__ __launch_bounds__(256, 3) void ffn2_kernel(
    const float* __restrict__ X, const __bf16* __restrict__ Agg,
    const __bf16* __restrict__ W2f, const float* __restrict__ b2f,
    float* __restrict__ out)
{
    const int wave = threadIdx.x >> 6;
    const int lane = threadIdx.x & 63;
    const int c = lane & 15, kh = lane >> 4;
    const int nh = wave & 1;       // col half (64 cols)
    const int rw = wave >> 1;      // row-tile wave within block

    float bias[4];
#pragma unroll
    for (int ntp = 0; ntp < 4; ++ntp) bias[ntp] = b2f[(nh * 4 + ntp) * 16 + c];

    const int NW = gridDim.x * 2;
    int tile = blockIdx.x * 2 + rw;

    f32x4 raw[8];
    bf16x8 rawg[4];
    if (tile * 16 < NN) {
        int rowA = tile * 16 + c; if (rowA >= NN) rowA = NN - 1;
        const float* xr = X + (size_t)rowA * DD + kh * 8;
        const __bf16* ar = Agg + (size_t)rowA * DD + kh * 8;
#pragma unroll
        for (int q = 0; q < 4; ++q) {
            raw[2 * q]     = *(const f32x4*)(xr + q * 32);
            raw[2 * q + 1] = *(const f32x4*)(xr + q * 32 + 4);
            rawg[q] = *(const bf16x8*)(ar + q * 32);
        }
    }

    while (tile * 16 < NN) {
        bf16x8 a[8];
#pragma unroll
        for (int kt = 0; kt < 4; ++kt) {
            bf16x8 fa;
#pragma unroll
            for (int i = 0; i < 4; ++i) {
                fa[i]     = (__bf16)raw[2 * kt][i];
                fa[4 + i] = (__bf16)raw[2 * kt + 1][i];
            }
            a[kt] = fa;
            a[4 + kt] = rawg[kt];
        }
        const int curtile = tile;
        tile += NW;
        if (tile * 16 < NN) {   // prefetch next tile
            int rowA = tile * 16 + c; if (rowA >= NN) rowA = NN - 1;
            const float* xr = X + (size_t)rowA * DD + kh * 8;
            const __bf16* ar = Agg + (size_t)rowA * DD + kh * 8;
#pragma unroll
            for (int q = 0; q < 4; ++q) {
                raw[2 * q]     = *(const f32x4*)(xr + q * 32);
                raw[2 * q + 1] = *(const f32x4*)(xr + q * 32 + 4);
                rawg[q] = *(const bf16x8*)(ar + q * 32);
            }
        }

        f32x4 acc[4] = {};
#pragma unroll
        for (int kt = 0; kt < 8; ++kt)
#pragma unroll
            for (int ntp = 0; ntp < 4; ++ntp) {
                bf16x8 bfr = *(const bf16x8*)(W2f + ((size_t)((kt * 8 + nh * 4 + ntp) * 64 + lane)) * 8);
                acc[ntp] = __builtin_amdgcn_mfma_f32_16x16x32_bf16(a[kt], bfr, acc[ntp], 0, 0, 0);
            }

#pragma unroll
        for (int r = 0; r < 4; ++r) {
            int row = curtile * 16 + kh * 4 + r;
            if (row < NN) {
#pragma unroll
                for (int ntp = 0; ntp < 4; ++ntp)
                    out[(size_t)row * DD + (nh * 4 + ntp) * 16 + c] =
                        gelu_fast(acc[ntp][r] + bias[ntp]);
            }
        }
    }
}

extern "C" void kernel_launch(void* const* d_in, const int* in_sizes, int n_in,
                              void* d_out, int out_size, void* d_ws, size_t ws_size,
                              hipStream_t stream) {
    const float* node_repr = (const float*)d_in[0];
    const int*   edges     = (const int*)d_in[1];
    const float* g1 = (const float*)d_in[2];
    const float* be1 = (const float*)d_in[3];
    const float* m1 = (const float*)d_in[4];
    const float* v1 = (const float*)d_in[5];
    const float* W1 = (const float*)d_in[6];
    const float* b1 = (const float*)d_in[7];
    const float* g2 = (const float*)d_in[8];
    const float* be2 = (const float*)d_in[9];
    const float* m2 = (const float*)d_in[10];
    const float* v2 = (const float*)d_in[11];
    const float* W2 = (const float*)d_in[12];
    const float* b2 = (const float*)d_in[13];

    char* ws = (char*)d_ws;
    __bf16* W1f = (__bf16*)(ws + W1F_OFF);
    __bf16* W2f = (__bf16*)(ws + W2F_OFF);
    float* b1f = (float*)(ws + B1F_OFF);
    float* b2f = (float*)(ws + B2F_OFF);
    __bf16* T  = (__bf16*)(ws + T_OFF);
    int* deg   = (int*)(ws + DEG_OFF);
    int* offs  = (int*)(ws + OFFS_OFF);
    int* cursor= (int*)(ws + CUR_OFF);
    int* elist = (int*)(ws + ELIST_OFF);
    int* bsum  = (int*)(ws + BSUM_OFF);
    int* boff  = (int*)(ws + BOFF_OFF);
    __bf16* Agg = (__bf16*)(ws + AGG_OFF);
    float* out = (float*)d_out;

    hipMemsetAsync(deg, 0, (size_t)NN * 4, stream);

    hipLaunchKernelGGL(fold_bias_kernel, dim3(64), dim3(256), 0, stream,
                       g1, be1, m1, v1, W1, b1, g2, be2, m2, v2, W2, b2, b1f, b2f);
    hipLaunchKernelGGL(fold_w_kernel, dim3(192), dim3(256), 0, stream,
                       g1, v1, W1, g2, v2, W2, W1f, W2f);

    hipLaunchKernelGGL(hist_kernel, dim3((EE + 255) / 256), dim3(256), 0, stream,
                       edges, deg);

    hipLaunchKernelGGL(ffn1_kernel, dim3(768), dim3(256), 0, stream,
                       node_repr, W1f, b1f, T);

    hipLaunchKernelGGL(scan_part_kernel, dim3(NBLK), dim3(256), 0, stream, deg, bsum);
    hipLaunchKernelGGL(scan_top_kernel, dim3(1), dim3(512), 0, stream, bsum, boff);
    hipLaunchKernelGGL(scan_final_kernel, dim3(NBLK), dim3(256), 0, stream, deg, boff, offs, cursor);

    hipLaunchKernelGGL(build_kernel, dim3((EE + 255) / 256), dim3(256), 0, stream,
                       edges, cursor, elist);

    hipLaunchKernelGGL(agg_kernel, dim3((NN * 16 + 255) / 256), dim3(256), 0, stream,
                       T, offs, deg, elist, Agg);

    hipLaunchKernelGGL(ffn2_kernel, dim3(768), dim3(256), 0, stream,
                       node_repr, Agg, W2f, b2f, out);
}

// Round 8
// 163.805 us; speedup vs baseline: 1.3315x; 1.3315x over previous
//
#include <hip/hip_runtime.h>

#define NN 100000
#define DD 128
#define EE 640000
#define BN_EPS 1e-3f
#define NBLK 391   // ceil(NN/256)
#define NTILE 6250 // NN/16 exactly

typedef __bf16 bf16x8 __attribute__((ext_vector_type(8)));
typedef float f32x4 __attribute__((ext_vector_type(4)));

// ---- workspace byte offsets ----
#define W1F_OFF 0u            // 128x128 bf16 frags    = 32768 B
#define W2F_OFF 32768u        // 256x128 bf16 frags    = 65536 B
#define B1F_OFF 98304u        // 128 f32
#define B2F_OFF 98816u        // 128 f32
#define T_OFF   99328u        // NN*128 bf16           = 25,600,000 B
#define DEG_OFF 25699328u     // NN int
#define OFFS_OFF 26099328u    // NN int
#define CUR_OFF 26499328u     // NN int
#define ELIST_OFF 26899328u   // EE int = 2,560,000 B
#define BSUM_OFF 29459328u    // NBLK int
#define BOFF_OFF 29461376u    // NBLK int
#define AGG_OFF 29464576u     // NN*128 bf16 = 25,600,000 B (end ~55.1 MB)

// tanh-form gelu: x * sigmoid(1.59576912*x + 0.07135481*x^3); max |err| vs exact ~3e-4
__device__ __forceinline__ float gelu_fast(float x) {
    float x3 = x * x * x;
    float z2 = 1.5957691216057308f * x + 0.07135481627002407f * x3;
    return x / (1.0f + __expf(-z2));
}

// bias fold: one wave per output column (256 waves total)
__global__ __launch_bounds__(256) void fold_bias_kernel(
    const float* __restrict__ g1, const float* __restrict__ be1,
    const float* __restrict__ m1, const float* __restrict__ v1,
    const float* __restrict__ W1, const float* __restrict__ b1,
    const float* __restrict__ g2, const float* __restrict__ be2,
    const float* __restrict__ m2, const float* __restrict__ v2,
    const float* __restrict__ W2, const float* __restrict__ b2,
    float* __restrict__ b1f, float* __restrict__ b2f)
{
    const int w = (blockIdx.x * 256 + threadIdx.x) >> 6;   // 0..255
    const int lane = threadIdx.x & 63;
    if (w < 128) {
        float acc = 0.f;
        for (int k = lane; k < 128; k += 64) {
            float s = g1[k] * rsqrtf(v1[k] + BN_EPS);
            float sh = be1[k] - m1[k] * s;
            acc += sh * W1[k * 128 + w];
        }
#pragma unroll
        for (int off = 32; off > 0; off >>= 1) acc += __shfl_down(acc, off);
        if (lane == 0) b1f[w] = acc + b1[w];
    } else {
        const int n = w - 128;
        float acc = 0.f;
        for (int k = lane; k < 256; k += 64) {
            float s = g2[k] * rsqrtf(v2[k] + BN_EPS);
            float sh = be2[k] - m2[k] * s;
            acc += sh * W2[k * 128 + n];
        }
#pragma unroll
        for (int off = 32; off > 0; off >>= 1) acc += __shfl_down(acc, off);
        if (lane == 0) b2f[n] = acc + b2[n];
    }
}

// weight fold into MFMA B-fragment order; grid covers 16384+32768 elements exactly.
// B-frag: lane l holds B[k=(l>>4)*8+i][n=(l&15)] per (kt,nt).
// agg-half rows of W2 permuted: physical col p -> logical col (p&7)*16 + (p>>3)
__global__ __launch_bounds__(256) void fold_w_kernel(
    const float* __restrict__ g1, const float* __restrict__ v1,
    const float* __restrict__ W1,
    const float* __restrict__ g2, const float* __restrict__ v2,
    const float* __restrict__ W2,
    __bf16* __restrict__ W1f, __bf16* __restrict__ W2f)
{
    int tid = blockIdx.x * 256 + threadIdx.x;
    if (tid < 16384) {
        int idx = tid;
        int i = idx & 7, l = (idx >> 3) & 63, nt = (idx >> 9) & 7, kt = idx >> 12;
        int k = kt * 32 + (l >> 4) * 8 + i;
        int n = nt * 16 + (l & 15);
        float s = g1[k] * rsqrtf(v1[k] + BN_EPS);
        W1f[idx] = (__bf16)(s * W1[k * 128 + n]);
    } else {
        int idx = tid - 16384;
        int i = idx & 7, l = (idx >> 3) & 63, nt = (idx >> 9) & 7, kt = idx >> 12;
        int n = nt * 16 + (l & 15);
        int row;
        if (kt < 4) {
            row = kt * 32 + (l >> 4) * 8 + i;
        } else {
            int q = (kt - 4) * 32 + (l >> 4) * 8 + i;      // physical agg col
            row = 128 + ((q & 7) * 16 + (q >> 3));          // logical W2 row
        }
        float s = g2[row] * rsqrtf(v2[row] + BN_EPS);
        W2f[idx] = (__bf16)(s * W2[row * 128 + n]);
    }
}

// t = gelu(X @ W1f + b1f); one 16-row tile per wave (R4 skeleton),
// B-frags from L1/L2 with register ping-pong: next kt-group's 8 loads are in
// flight during the current group's 8 MFMAs (counted vmcnt, no LDS/barrier).
// T stored bf16 with permuted cols: physical p -> logical (p&7)*16 + (p>>3)
__global__ __launch_bounds__(256) void ffn1_kernel(
    const float* __restrict__ X, const __bf16* __restrict__ W1f,
    const float* __restrict__ b1f, __bf16* __restrict__ T)
{
    const int wave = threadIdx.x >> 6;
    const int lane = threadIdx.x & 63;
    const int tile = blockIdx.x * 4 + wave;
    if (tile >= NTILE) return;
    const int c = lane & 15, kh = lane >> 4;

    const int rowA = tile * 16 + c;
    const float* xr = X + (size_t)rowA * DD + kh * 8;

    // issue all A loads
    f32x4 r0[4], r1[4];
#pragma unroll
    for (int q = 0; q < 4; ++q) {
        r0[q] = *(const f32x4*)(xr + q * 32);
        r1[q] = *(const f32x4*)(xr + q * 32 + 4);
    }
    // B group 0 in flight too
    bf16x8 bp[8], bq[8];
#pragma unroll
    for (int nt = 0; nt < 8; ++nt)
        bp[nt] = *(const bf16x8*)(W1f + ((size_t)(nt * 64 + lane)) * 8);

    bf16x8 af[4];
#pragma unroll
    for (int kt = 0; kt < 4; ++kt) {
        bf16x8 fa;
#pragma unroll
        for (int i = 0; i < 4; ++i) { fa[i] = (__bf16)r0[kt][i]; fa[4 + i] = (__bf16)r1[kt][i]; }
        af[kt] = fa;
    }

    f32x4 acc[8] = {};
#pragma unroll
    for (int kt = 0; kt < 4; ++kt) {
        if (kt + 1 < 4) {   // prefetch next kt-group into the other buffer
#pragma unroll
            for (int nt = 0; nt < 8; ++nt) {
                bf16x8 v = *(const bf16x8*)(W1f + ((size_t)(((kt + 1) * 8 + nt) * 64 + lane)) * 8);
                if (kt & 1) bp[nt] = v; else bq[nt] = v;
            }
        }
#pragma unroll
        for (int nt = 0; nt < 8; ++nt) {
            bf16x8 cur = (kt & 1) ? bq[nt] : bp[nt];
            acc[nt] = __builtin_amdgcn_mfma_f32_16x16x32_bf16(af[kt], cur, acc[nt], 0, 0, 0);
        }
    }

    float bias[8];
#pragma unroll
    for (int nt = 0; nt < 8; ++nt) bias[nt] = b1f[nt * 16 + c];

#pragma unroll
    for (int r = 0; r < 4; ++r) {
        int row = tile * 16 + kh * 4 + r;
        bf16x8 o;
#pragma unroll
        for (int nt = 0; nt < 8; ++nt)
            o[nt] = (__bf16)gelu_fast(acc[nt][r] + bias[nt]);
        *(bf16x8*)(T + (size_t)row * DD + c * 8) = o;
    }
}

// deg[dst]++ over all edges
__global__ __launch_bounds__(256) void hist_kernel(const int* __restrict__ edges,
                                                   int* __restrict__ deg)
{
    int e = blockIdx.x * 256 + threadIdx.x;
    if (e < EE) atomicAdd(&deg[edges[e]], 1);
}

// phase 1: per-block sum of deg
__global__ __launch_bounds__(256) void scan_part_kernel(const int* __restrict__ deg,
                                                        int* __restrict__ bsum)
{
    int i = blockIdx.x * 256 + threadIdx.x;
    int v = (i < NN) ? deg[i] : 0;
#pragma unroll
    for (int off = 32; off > 0; off >>= 1) v += __shfl_down(v, off);
    __shared__ int ws[4];
    if ((threadIdx.x & 63) == 0) ws[threadIdx.x >> 6] = v;
    __syncthreads();
    if (threadIdx.x == 0) bsum[blockIdx.x] = ws[0] + ws[1] + ws[2] + ws[3];
}

// phase 2: single-block exclusive scan of NBLK block sums
__global__ __launch_bounds__(512) void scan_top_kernel(const int* __restrict__ bsum,
                                                       int* __restrict__ boff)
{
    __shared__ int s[512];
    const int t = threadIdx.x;
    int v = (t < NBLK) ? bsum[t] : 0;
    s[t] = v;
    __syncthreads();
    for (int off = 1; off < 512; off <<= 1) {
        int tmp = (t >= off) ? s[t - off] : 0;
        __syncthreads();
        s[t] += tmp;
        __syncthreads();
    }
    if (t < NBLK) boff[t] = s[t] - v;
}

// phase 3: per-block exclusive scan + block offset -> offs, cursor
__global__ __launch_bounds__(256) void scan_final_kernel(const int* __restrict__ deg,
                                                         const int* __restrict__ boff,
                                                         int* __restrict__ offs,
                                                         int* __restrict__ cursor)
{
    __shared__ int s[256];
    const int t = threadIdx.x;
    int i = blockIdx.x * 256 + t;
    int v = (i < NN) ? deg[i] : 0;
    s[t] = v;
    __syncthreads();
    for (int off = 1; off < 256; off <<= 1) {
        int tmp = (t >= off) ? s[t - off] : 0;
        __syncthreads();
        s[t] += tmp;
        __syncthreads();
    }
    int ex = s[t] - v + boff[blockIdx.x];
    if (i < NN) { offs[i] = ex; cursor[i] = ex; }
}

// CSR edge list: elist[offs[dst] ...] = src
__global__ __launch_bounds__(256) void build_kernel(const int* __restrict__ edges,
                                                    int* __restrict__ cursor,
                                                    int* __restrict__ elist)
{
    int e = blockIdx.x * 256 + threadIdx.x;
    if (e >= EE) return;
    int dst = edges[e];
    int src = edges[EE + e];
    int pos = atomicAdd(&cursor[dst], 1);
    elist[pos] = src;
}

// gather-mean: Agg[node] = mean of T[src] rows (permuted layout kept).
// 16 threads/node, 4-edge unroll for 4 independent loads in flight.
__global__ __launch_bounds__(256) void agg_kernel(
    const __bf16* __restrict__ T, const int* __restrict__ offs,
    const int* __restrict__ deg, const int* __restrict__ elist,
    __bf16* __restrict__ Agg)
{
    int t = blockIdx.x * 256 + threadIdx.x;
    int node = t >> 4, j = t & 15;
    if (node >= NN) return;
    const int beg = offs[node];
    const int d = deg[node];
    const int end = beg + d;
    float acc[8] = {};
    int e = beg;
    for (; e + 3 < end; e += 4) {
        int s0 = elist[e], s1 = elist[e + 1], s2 = elist[e + 2], s3 = elist[e + 3];
        bf16x8 v0 = *(const bf16x8*)(T + (size_t)s0 * DD + j * 8);
        bf16x8 v1 = *(const bf16x8*)(T + (size_t)s1 * DD + j * 8);
        bf16x8 v2 = *(const bf16x8*)(T + (size_t)s2 * DD + j * 8);
        bf16x8 v3 = *(const bf16x8*)(T + (size_t)s3 * DD + j * 8);
#pragma unroll
        for (int i = 0; i < 8; ++i)
            acc[i] += ((float)v0[i] + (float)v1[i]) + ((float)v2[i] + (float)v3[i]);
    }
    for (; e < end; ++e) {
        int s0 = elist[e];
        bf16x8 v0 = *(const bf16x8*)(T + (size_t)s0 * DD + j * 8);
#pragma unroll
        for (int i = 0; i < 8; ++i) acc[i] += (float)v0[i];
    }
    const float inv = 1.0f / fmaxf((float)d, 1.0f);
    bf16x8 o;
#pragma unroll
    for (int i = 0; i < 8; ++i) o[i] = (__bf16)(acc[i] * inv);
    *(bf16x8*)(Agg + (size_t)node * DD + j * 8) = o;
}

// out = gelu([X, Agg] @ W2f + b2f); one 16-row tile per wave, full 128 cols.
// 8 kt-groups with register ping-pong B prefetch; nontemporal out stores.
__global__ __launch_bounds__(256) void ffn2_kernel(
    const float* __restrict__ X, const __bf16* __restrict__ Agg,
    const __bf16* __restrict__ W2f, const float* __restrict__ b2f,
    float* __restrict__ out)
{
    const int wave = threadIdx.x >> 6;
    const int lane = threadIdx.x & 63;
    const int tile = blockIdx.x * 4 + wave;
    if (tile >= NTILE) return;
    const int c = lane & 15, kh = lane >> 4;

    const int rowA = tile * 16 + c;
    const float* xr = X + (size_t)rowA * DD + kh * 8;
    const __bf16* ar = Agg + (size_t)rowA * DD + kh * 8;

    // issue all A loads (X f32 + Agg bf16)
    f32x4 r0[4], r1[4];
    bf16x8 ag[4];
#pragma unroll
    for (int q = 0; q < 4; ++q) {
        r0[q] = *(const f32x4*)(xr + q * 32);
        r1[q] = *(const f32x4*)(xr + q * 32 + 4);
        ag[q] = *(const bf16x8*)(ar + q * 32);
    }
    // B group 0 in flight
    bf16x8 bp[8], bq[8];
#pragma unroll
    for (int nt = 0; nt < 8; ++nt)
        bp[nt] = *(const bf16x8*)(W2f + ((size_t)(nt * 64 + lane)) * 8);

    bf16x8 a[8];
#pragma unroll
    for (int kt = 0; kt < 4; ++kt) {
        bf16x8 fa;
#pragma unroll
        for (int i = 0; i < 4; ++i) { fa[i] = (__bf16)r0[kt][i]; fa[4 + i] = (__bf16)r1[kt][i]; }
        a[kt] = fa;
        a[4 + kt] = ag[kt];
    }

    f32x4 acc[8] = {};
#pragma unroll
    for (int kt = 0; kt < 8; ++kt) {
        if (kt + 1 < 8) {   // prefetch next kt-group
#pragma unroll
            for (int nt = 0; nt < 8; ++nt) {
                bf16x8 v = *(const bf16x8*)(W2f + ((size_t)(((kt + 1) * 8 + nt) * 64 + lane)) * 8);
                if (kt & 1) bp[nt] = v; else bq[nt] = v;
            }
        }
#pragma unroll
        for (int nt = 0; nt < 8; ++nt) {
            bf16x8 cur = (kt & 1) ? bq[nt] : bp[nt];
            acc[nt] = __builtin_amdgcn_mfma_f32_16x16x32_bf16(a[kt], cur, acc[nt], 0, 0, 0);
        }
    }

    float bias[8];
#pragma unroll
    for (int nt = 0; nt < 8; ++nt) bias[nt] = b2f[nt * 16 + c];

#pragma unroll
    for (int r = 0; r < 4; ++r) {
        int row = tile * 16 + kh * 4 + r;
#pragma unroll
        for (int nt = 0; nt < 8; ++nt)
            __builtin_nontemporal_store(gelu_fast(acc[nt][r] + bias[nt]),
                                        &out[(size_t)row * DD + nt * 16 + c]);
    }
}

extern "C" void kernel_launch(void* const* d_in, const int* in_sizes, int n_in,
                              void* d_out, int out_size, void* d_ws, size_t ws_size,
                              hipStream_t stream) {
    const float* node_repr = (const float*)d_in[0];
    const int*   edges     = (const int*)d_in[1];
    const float* g1 = (const float*)d_in[2];
    const float* be1 = (const float*)d_in[3];
    const float* m1 = (const float*)d_in[4];
    const float* v1 = (const float*)d_in[5];
    const float* W1 = (const float*)d_in[6];
    const float* b1 = (const float*)d_in[7];
    const float* g2 = (const float*)d_in[8];
    const float* be2 = (const float*)d_in[9];
    const float* m2 = (const float*)d_in[10];
    const float* v2 = (const float*)d_in[11];
    const float* W2 = (const float*)d_in[12];
    const float* b2 = (const float*)d_in[13];

    char* ws = (char*)d_ws;
    __bf16* W1f = (__bf16*)(ws + W1F_OFF);
    __bf16* W2f = (__bf16*)(ws + W2F_OFF);
    float* b1f = (float*)(ws + B1F_OFF);
    float* b2f = (float*)(ws + B2F_OFF);
    __bf16* T  = (__bf16*)(ws + T_OFF);
    int* deg   = (int*)(ws + DEG_OFF);
    int* offs  = (int*)(ws + OFFS_OFF);
    int* cursor= (int*)(ws + CUR_OFF);
    int* elist = (int*)(ws + ELIST_OFF);
    int* bsum  = (int*)(ws + BSUM_OFF);
    int* boff  = (int*)(ws + BOFF_OFF);
    __bf16* Agg = (__bf16*)(ws + AGG_OFF);
    float* out = (float*)d_out;

    hipMemsetAsync(deg, 0, (size_t)NN * 4, stream);

    hipLaunchKernelGGL(fold_bias_kernel, dim3(64), dim3(256), 0, stream,
                       g1, be1, m1, v1, W1, b1, g2, be2, m2, v2, W2, b2, b1f, b2f);
    hipLaunchKernelGGL(fold_w_kernel, dim3(192), dim3(256), 0, stream,
                       g1, v1, W1, g2, v2, W2, W1f, W2f);

    hipLaunchKernelGGL(hist_kernel, dim3((EE + 255) / 256), dim3(256), 0, stream,
                       edges, deg);

    hipLaunchKernelGGL(ffn1_kernel, dim3((NTILE + 3) / 4), dim3(256), 0, stream,
                       node_repr, W1f, b1f, T);

    hipLaunchKernelGGL(scan_part_kernel, dim3(NBLK), dim3(256), 0, stream, deg, bsum);
    hipLaunchKernelGGL(scan_top_kernel, dim3(1), dim3(512), 0, stream, bsum, boff);
    hipLaunchKernelGGL(scan_final_kernel, dim3(NBLK), dim3(256), 0, stream, deg, boff, offs, cursor);

    hipLaunchKernelGGL(build_kernel, dim3((EE + 255) / 256), dim3(256), 0, stream,
                       edges, cursor, elist);

    hipLaunchKernelGGL(agg_kernel, dim3((NN * 16 + 255) / 256), dim3(256), 0, stream,
                       T, offs, deg, elist, Agg);

    hipLaunchKernelGGL(ffn2_kernel, dim3((NTILE + 3) / 4), dim3(256), 0, stream,
                       node_repr, Agg, W2f, b2f, out);
}